// Round 11
// baseline (268.159 us; speedup 1.0000x reference)
//
#include <hip/hip_runtime.h>

typedef unsigned short u16;
typedef __bf16 bf16_t;
typedef bf16_t bf16x8 __attribute__((ext_vector_type(8)));
typedef float f32x4 __attribute__((ext_vector_type(4)));

static __device__ __forceinline__ u16 f2bf(float f) {
  unsigned u = __builtin_bit_cast(unsigned, f);
  u += 0x7FFFu + ((u >> 16) & 1u);
  return (u16)(u >> 16);
}
static __device__ __forceinline__ bf16x8 ldfrag(const u16* p) {
  return __builtin_bit_cast(bf16x8, *(const uint4*)p);
}
static __device__ __forceinline__ float fexp2(float x) {
#if __has_builtin(__builtin_amdgcn_exp2f)
  return __builtin_amdgcn_exp2f(x);
#else
  return __expf(x * 0.69314718056f);
#endif
}
// pack [hi.b3 hi.b2 lo.b3 lo.b2] (two bf16 = fp32 high halves, RTZ)
static __device__ __forceinline__ unsigned pack_hi16(unsigned hi, unsigned lo) {
#if __has_builtin(__builtin_amdgcn_perm)
  return __builtin_amdgcn_perm(hi, lo, 0x07060302u);
#else
  return (lo >> 16) | (hi & 0xFFFF0000u);
#endif
}
// XOR-swizzled tile: logical (row, 8-elem chunk) -> u16 offset, stride 64.
static __device__ __forceinline__ int sw(int row, int chunk) {
  return (row << 6) + ((chunk ^ (row & 7)) << 3);
}

#define XSZ 3145728   // 2*2048*768
#define QWSZ 1769472  // 2304*768
#define PWSZ 589824   // 768*768

// fp32 -> bf16 (RNE) one-shot conversion of x and the two weight matrices.
__global__ __launch_bounds__(256) void convert_all(
    const float* __restrict__ x, const float* __restrict__ qw,
    const float* __restrict__ pw, u16* __restrict__ xb,
    u16* __restrict__ qwb, u16* __restrict__ pwb)
{
  const int i = (blockIdx.x * 256 + threadIdx.x) * 8;
  const float* src; u16* dst; int off;
  if (i < XSZ) { src = x; dst = xb; off = i; }
  else if (i < XSZ + QWSZ) { src = qw; dst = qwb; off = i - XSZ; }
  else { src = pw; dst = pwb; off = i - (XSZ + QWSZ); }
  float4 a = *(const float4*)(src + off), b = *(const float4*)(src + off + 4);
  u16 t[8] = {f2bf(a.x), f2bf(a.y), f2bf(a.z), f2bf(a.w),
              f2bf(b.x), f2bf(b.y), f2bf(b.z), f2bf(b.w)};
  *(uint4*)(dst + off) = *(const uint4*)t;
}

// ---------------------------------------------------------------------------
// NT GEMM (all-bf16): C[m,n] = sum_k A[m,k] W[n,k] + bias[n]. K=768.
// BM=64, BN=128, swizzled LDS (48 KB), double-buffered, register prefetch,
// ONE barrier per K-iter, 3 blocks/CU.
// MODE 0: A=xb [B,N,C], grid(18,64): q,k -> [BH,N,D], V^T fused
// MODE 1: A=o1 [N,B,C], grid(6,64): fused L2-normalize -> st
// MODE 2: A=o2 [N,B,C], grid(6,64): -> fp32 d_out [B,N,C]
// ---------------------------------------------------------------------------
template<int MODE>
__global__ __launch_bounds__(256, 3) void gemm_nt(
    const u16* __restrict__ A, const u16* __restrict__ W,
    const float* __restrict__ bias,
    u16* __restrict__ d0, u16* __restrict__ d1, u16* __restrict__ d2,
    float* __restrict__ df)
{
  __shared__ __align__(16) u16 sA[2][64 * 64];
  __shared__ __align__(16) u16 sB[2][128 * 64];
  const int tid = threadIdx.x;
  const int m0 = blockIdx.y * 64, n0 = blockIdx.x * 128;
  const int w = tid >> 6, lane = tid & 63, l16 = lane & 15, quad = lane >> 4;
  const int wm = (w >> 1) * 32, wn = (w & 1) * 64;

  f32x4 acc[2][4] = {};
  const int sr = tid >> 3, ch = tid & 7, sc = ch * 8;

  #pragma unroll
  for (int p = 0; p < 2; p++)
    *(uint4*)(sA[0] + sw(sr + p * 32, ch)) =
        *(const uint4*)(A + (size_t)(m0 + sr + p * 32) * 768 + sc);
  #pragma unroll
  for (int p = 0; p < 4; p++)
    *(uint4*)(sB[0] + sw(sr + p * 32, ch)) =
        *(const uint4*)(W + (size_t)(n0 + sr + p * 32) * 768 + sc);
  __syncthreads();

  for (int kt = 0; kt < 12; kt++) {
    const int buf = kt & 1;
    const bool pre = (kt + 1 < 12);
    uint4 rab[2], rb[4];
    if (pre) {
      const int kc = (kt + 1) * 64 + sc;
      #pragma unroll
      for (int p = 0; p < 2; p++)
        rab[p] = *(const uint4*)(A + (size_t)(m0 + sr + p * 32) * 768 + kc);
      #pragma unroll
      for (int p = 0; p < 4; p++)
        rb[p] = *(const uint4*)(W + (size_t)(n0 + sr + p * 32) * 768 + kc);
    }
    #pragma unroll
    for (int ks = 0; ks < 2; ks++) {
      bf16x8 af[2], bfv[4];
      #pragma unroll
      for (int i = 0; i < 2; i++)
        af[i] = ldfrag(sA[buf] + sw(wm + i * 16 + l16, ks * 4 + quad));
      #pragma unroll
      for (int i = 0; i < 4; i++)
        bfv[i] = ldfrag(sB[buf] + sw(wn + i * 16 + l16, ks * 4 + quad));
      #pragma unroll
      for (int mi = 0; mi < 2; mi++)
        #pragma unroll
        for (int ni = 0; ni < 4; ni++)
          acc[mi][ni] = __builtin_amdgcn_mfma_f32_16x16x32_bf16(af[mi], bfv[ni], acc[mi][ni], 0, 0, 0);
    }
    if (pre) {
      #pragma unroll
      for (int p = 0; p < 2; p++)
        *(uint4*)(sA[buf ^ 1] + sw(sr + p * 32, ch)) = rab[p];
      #pragma unroll
      for (int p = 0; p < 4; p++)
        *(uint4*)(sB[buf ^ 1] + sw(sr + p * 32, ch)) = rb[p];
    }
    __syncthreads();
  }

  if (MODE == 0) {
    #pragma unroll
    for (int ni = 0; ni < 4; ni++) {
      const int gn = n0 + wn + ni * 16 + l16;
      const float bv = bias[gn];
      const int which = gn / 768;
      const int c = gn - which * 768, hh = c >> 6, d = c & 63;
      #pragma unroll
      for (int mi = 0; mi < 2; mi++) {
        const int gm0 = m0 + wm + mi * 16 + quad * 4;
        const int bb = gm0 >> 11, nt0 = gm0 & 2047;
        if (which == 2) {
          u16 t[4];
          #pragma unroll
          for (int r = 0; r < 4; r++) t[r] = f2bf(acc[mi][ni][r] + bv);
          *(uint2*)(d2 + (((size_t)(bb * 12 + hh)) * 64 + d) * 2048 + nt0) =
              *(const uint2*)t;
        } else {
          u16* dst = (which == 0) ? d0 : d1;
          #pragma unroll
          for (int r = 0; r < 4; r++)
            dst[(((size_t)(bb * 12 + hh)) * 2048 + nt0 + r) * 64 + d] =
                f2bf(acc[mi][ni][r] + bv);
        }
      }
    }
  } else if (MODE == 1) {
    #pragma unroll
    for (int mi = 0; mi < 2; mi++) {
      #pragma unroll
      for (int r = 0; r < 4; r++) {
        float v[4]; float ss = 0.f;
        #pragma unroll
        for (int ni = 0; ni < 4; ni++) {
          v[ni] = acc[mi][ni][r] + bias[n0 + wn + ni * 16 + l16];
          ss += v[ni] * v[ni];
        }
        #pragma unroll
        for (int off = 1; off < 16; off <<= 1) ss += __shfl_xor(ss, off);
        const float scl = 1.f / fmaxf(sqrtf(ss), 1e-12f);
        const int gm = m0 + wm + mi * 16 + quad * 4 + r;
        const int nt = gm >> 1, b = gm & 1;
        #pragma unroll
        for (int ni = 0; ni < 4; ni++) {
          const int gn = n0 + wn + ni * 16 + l16, h = gn >> 6, d = gn & 63;
          d0[(((size_t)(b * 12 + h)) * 2048 + nt) * 64 + d] = f2bf(v[ni] * scl);
        }
      }
    }
  } else {
    #pragma unroll
    for (int ni = 0; ni < 4; ni++) {
      const int gn = n0 + wn + ni * 16 + l16;
      const float bv = bias[gn];
      #pragma unroll
      for (int mi = 0; mi < 2; mi++) {
        #pragma unroll
        for (int r = 0; r < 4; r++) {
          const int gm = m0 + wm + mi * 16 + quad * 4 + r;
          const int nt = gm >> 1, b = gm & 1;
          df[((size_t)b * 2048 + nt) * 768 + gn] = acc[mi][ni][r] + bv;
        }
      }
    }
  }
}

// ---------------------------------------------------------------------------
// Flash attention, S^T form, KEY-SPLIT x4, Q-tile 256. 4 waves; each wave
// owns 64 queries (4 groups of 16 sharing all K/V fragment reads -> 1.6x
// less LDS work than 2 groups). Double-buffered K/V, ONE barrier per iter.
// Each block does a QUARTER of the keys (8 j-iters), stores f32 partial
// numerators (256q x 64d) + partial l. blockIdx.x = qt*4 + quarter.
// MODE 1: s*0.125;  MODE 2: s*10, s<0 masked.
// ---------------------------------------------------------------------------
template<int MODE>
__global__ __launch_bounds__(256, 2) void flash_attn(
    const u16* __restrict__ Qm, const u16* __restrict__ Km,
    const u16* __restrict__ VT,
    float* __restrict__ partN, float* __restrict__ partL)
{
  constexpr int N = 2048;
  __shared__ __align__(16) u16 sU[256 * 64];  // 32 KB: Q staging, then P
  __shared__ __align__(16) u16 sK[2][64 * 64];
  __shared__ __align__(16) u16 sVT[2][64 * 64];
  const int tid = threadIdx.x;
  const int bh = blockIdx.y;
  const int qt = blockIdx.x >> 2, quarter = blockIdx.x & 3;
  const int m0 = qt * 256, j0 = quarter * 512;
  const int w = tid >> 6, lane = tid & 63, l16 = lane & 15, quad = lane >> 4;

  constexpr float SC = (MODE == 1) ? 0.18033688011112042f   // 0.125*log2(e)
                                   : 14.426950408889634f;   // 10*log2(e)
  constexpr float M0 = (MODE == 1) ? 24.f : 14.6f;

  const u16* kbase = Km + (size_t)bh * N * 64;
  const u16* vbase = VT + (size_t)bh * 64 * N;
  // Q staging: 256 rows, one row per thread (8 uint4 each)
  // K/V staging: 64 rows x 8 chunks = 512 uint4 over 256 threads (2 each)
  const int sr4 = tid >> 2, c4 = tid & 3;
  {
    const u16* qp = Qm + ((size_t)bh * N + m0 + tid) * 64;
    #pragma unroll
    for (int j = 0; j < 8; j++)
      *(uint4*)(sU + sw(tid, j)) = *(const uint4*)(qp + j * 8);
    const u16* kp = kbase + (size_t)(j0 + sr4) * 64;
    *(uint4*)(sK[0] + sw(sr4, c4))     = *(const uint4*)(kp + c4 * 8);
    *(uint4*)(sK[0] + sw(sr4, c4 + 4)) = *(const uint4*)(kp + c4 * 8 + 32);
    const u16* vp = vbase + (size_t)sr4 * N + j0;
    *(uint4*)(sVT[0] + sw(sr4, c4))     = *(const uint4*)(vp + c4 * 8);
    *(uint4*)(sVT[0] + sw(sr4, c4 + 4)) = *(const uint4*)(vp + c4 * 8 + 32);
  }
  __syncthreads();
  bf16x8 qf[4][2];
  #pragma unroll
  for (int qg = 0; qg < 4; qg++) {
    qf[qg][0] = ldfrag(sU + sw(w * 64 + qg * 16 + l16, quad));
    qf[qg][1] = ldfrag(sU + sw(w * 64 + qg * 16 + l16, quad + 4));
  }
  asm volatile("s_waitcnt lgkmcnt(0)" ::: "memory");  // qf in regs before P overlays

  bf16x8 ones;
  #pragma unroll
  for (int i = 0; i < 8; i++) ones[i] = (bf16_t)1.0f;

  f32x4 oacc[4][4] = {};
  f32x4 lacc[4] = {};

  for (int it = 0; it < 8; it++) {
    const int buf = it & 1;
    const u16* sKb = sK[buf];
    const u16* sVb = sVT[buf];
    u16* sKn = sK[buf ^ 1];
    u16* sVn = sVT[buf ^ 1];

    uint4 pk0, pk1, pv0, pv1;
    const bool pre = (it + 1 < 8);
    if (pre) {  // register prefetch of next tile
      const int j1 = j0 + (it + 1) * 64;
      const u16* kp = kbase + (size_t)(j1 + sr4) * 64;
      pk0 = *(const uint4*)(kp + c4 * 8);
      pk1 = *(const uint4*)(kp + c4 * 8 + 32);
      const u16* vp = vbase + (size_t)sr4 * N + j1;
      pv0 = *(const uint4*)(vp + c4 * 8);
      pv1 = *(const uint4*)(vp + c4 * 8 + 32);
    }

    // S^T per jt; exp fused immediately (bounds live VGPRs)
    #pragma unroll
    for (int jt = 0; jt < 4; jt++) {
      bf16x8 kf0 = ldfrag(sKb + sw(jt * 16 + l16, quad));
      bf16x8 kf1 = ldfrag(sKb + sw(jt * 16 + l16, quad + 4));
      #pragma unroll
      for (int qg = 0; qg < 4; qg++) {
        f32x4 a = {};
        a = __builtin_amdgcn_mfma_f32_16x16x32_bf16(kf0, qf[qg][0], a, 0, 0, 0);
        a = __builtin_amdgcn_mfma_f32_16x16x32_bf16(kf1, qf[qg][1], a, 0, 0, 0);
        unsigned pu[4];
        #pragma unroll
        for (int r = 0; r < 4; r++) {
          float p = fexp2(fmaf(a[r], SC, -M0));
          if (MODE == 2 && a[r] < 0.f) p = 0.f;
          pu[r] = __builtin_bit_cast(unsigned, p) & 0xFFFF0000u;
        }
        uint2 pkk;
        pkk.x = pack_hi16(pu[1], pu[0]);
        pkk.y = pack_hi16(pu[3], pu[2]);
        const int prow = w * 64 + qg * 16 + l16;
        *(uint2*)(sU + sw(prow, 2 * jt + (quad >> 1)) + (quad & 1) * 4) = pkk;
      }
    }

    // wave-local drain: P writes complete before B-layout re-read
    asm volatile("s_waitcnt lgkmcnt(0)" ::: "memory");
    bf16x8 pf[4][2];
    #pragma unroll
    for (int qg = 0; qg < 4; qg++) {
      pf[qg][0] = ldfrag(sU + sw(w * 64 + qg * 16 + l16, quad));
      pf[qg][1] = ldfrag(sU + sw(w * 64 + qg * 16 + l16, quad + 4));
    }

    if (pre) {  // LDS-write prefetched tile (other buffer, no reader yet)
      *(uint4*)(sKn + sw(sr4, c4))     = pk0;
      *(uint4*)(sKn + sw(sr4, c4 + 4)) = pk1;
      *(uint4*)(sVn + sw(sr4, c4))     = pv0;
      *(uint4*)(sVn + sw(sr4, c4 + 4)) = pv1;
    }

    // O^T = V^T . P^T ; l = ones . P^T ; vf shared across 4 query groups
    #pragma unroll
    for (int d4 = 0; d4 < 4; d4++) {
      bf16x8 v0 = ldfrag(sVb + sw(d4 * 16 + l16, quad));
      bf16x8 v1 = ldfrag(sVb + sw(d4 * 16 + l16, quad + 4));
      #pragma unroll
      for (int qg = 0; qg < 4; qg++) {
        oacc[qg][d4] = __builtin_amdgcn_mfma_f32_16x16x32_bf16(v0, pf[qg][0], oacc[qg][d4], 0, 0, 0);
        oacc[qg][d4] = __builtin_amdgcn_mfma_f32_16x16x32_bf16(v1, pf[qg][1], oacc[qg][d4], 0, 0, 0);
      }
    }
    #pragma unroll
    for (int qg = 0; qg < 4; qg++) {
      lacc[qg] = __builtin_amdgcn_mfma_f32_16x16x32_bf16(ones, pf[qg][0], lacc[qg], 0, 0, 0);
      lacc[qg] = __builtin_amdgcn_mfma_f32_16x16x32_bf16(ones, pf[qg][1], lacc[qg], 0, 0, 0);
    }
    __syncthreads();  // buf consumed by all waves; next buf visible
  }

  // store partials: thread-flat, 16384 floats per block
  const int blk = bh * 32 + blockIdx.x;
  float* pN = partN + (size_t)blk * 16384 + tid * 64;
  #pragma unroll
  for (int qg = 0; qg < 4; qg++) {
    #pragma unroll
    for (int d4 = 0; d4 < 4; d4++)
      *(f32x4*)(pN + qg * 16 + d4 * 4) = oacc[qg][d4];
    if (quad == 0)
      partL[blk * 256 + w * 64 + qg * 16 + l16] = lacc[qg][0];
  }
}

// Combine the four key-quarters: O = sum(n_i)/sum(l_i), write [N,B,C] bf16.
__global__ __launch_bounds__(256) void combine_flash(
    const float* __restrict__ partN, const float* __restrict__ partL,
    u16* __restrict__ Ob)
{
  const int bh = blockIdx.x >> 3, qt = blockIdx.x & 7;  // 24*8 = 192 blocks
  const int b = bh / 12, h = bh % 12;
  const int m0 = qt * 256;
  const int tid = threadIdx.x;
  const int w = tid >> 6, lane = tid & 63, l16 = lane & 15, quad = lane >> 4;
  const int blkbase = bh * 32 + qt * 4;
  const float* n0 = partN + (size_t)(blkbase + 0) * 16384 + tid * 64;
  const float* n1 = partN + (size_t)(blkbase + 1) * 16384 + tid * 64;
  const float* n2 = partN + (size_t)(blkbase + 2) * 16384 + tid * 64;
  const float* n3 = partN + (size_t)(blkbase + 3) * 16384 + tid * 64;
  #pragma unroll
  for (int qg = 0; qg < 4; qg++) {
    const int qrow = w * 64 + qg * 16 + l16;
    const float l = partL[(blkbase + 0) * 256 + qrow] +
                    partL[(blkbase + 1) * 256 + qrow] +
                    partL[(blkbase + 2) * 256 + qrow] +
                    partL[(blkbase + 3) * 256 + qrow];
    const float inv = 1.f / fmaxf(l, 1e-30f);
    const int query = m0 + qrow;
    u16* obase = Ob + ((size_t)query * 2 + b) * 768 + h * 64;
    #pragma unroll
    for (int d4 = 0; d4 < 4; d4++) {
      const int o = qg * 16 + d4 * 4;
      float4 a = *(const float4*)(n0 + o);
      float4 c = *(const float4*)(n1 + o);
      float4 e = *(const float4*)(n2 + o);
      float4 g = *(const float4*)(n3 + o);
      u16 t[4] = {f2bf((a.x + c.x + e.x + g.x) * inv),
                  f2bf((a.y + c.y + e.y + g.y) * inv),
                  f2bf((a.z + c.z + e.z + g.z) * inv),
                  f2bf((a.w + c.w + e.w + g.w) * inv)};
      *(uint2*)(obase + d4 * 16 + quad * 4) = *(const uint2*)t;
    }
  }
}

extern "C" void kernel_launch(void* const* d_in, const int* in_sizes, int n_in,
                              void* d_out, int out_size, void* d_ws, size_t ws_size,
                              hipStream_t stream) {
  const float* x      = (const float*)d_in[0];
  const float* qkv_w  = (const float*)d_in[1];
  const float* qkv_b  = (const float*)d_in[2];
  const float* proj_w = (const float*)d_in[3];
  const float* proj_b = (const float*)d_in[4];
  float* out = (float*)d_out;

  const size_t SZ = (size_t)24 * 2048 * 64;  // elems per [BH,N,D] buffer
  char* ws = (char*)d_ws;
  u16* vtb = (u16*)ws;                                     // 6.29 MB
  size_t off = SZ * 2;
  u16* pwb = (u16*)(ws + off); off += (size_t)PWSZ * 2;    // 1.18 MB
  u16* qb  = (u16*)(ws + off); off += SZ * 2;              // 6.29 MB
  u16* kb  = (u16*)(ws + off); off += SZ * 2;              // 6.29 MB
  float* partN = (float*)(ws + off); off += (size_t)768 * 16384 * 4;  // 50.3 MB
  float* partL = (float*)(ws + off); off += (size_t)768 * 256 * 4;    // 0.79 MB
  // overlays (time-disjoint): xb and qwb live inside partN's region (both
  // dead after gemm0; partN first written in flash1). o1/o2 reuse qb (dead
  // after flash1); st reuses kb (dead after flash1).
  u16* xb  = (u16*)partN;                  // 6.29 MB
  u16* qwb = (u16*)partN + XSZ;            // 3.54 MB
  u16* o1 = qb;
  u16* o2 = qb;
  u16* st = kb;
  // total ws use ~71 MB

  convert_all<<<2688, 256, 0, stream>>>(x, qkv_w, proj_w, xb, qwb, pwb);
  // q,k -> [BH,N,D]; V^T -> [BH,D,N] (transpose fused into epilogue)
  gemm_nt<0><<<dim3(18, 64), 256, 0, stream>>>(xb, qwb, qkv_b, qb, kb, vtb, nullptr);
  flash_attn<1><<<dim3(32, 24), 256, 0, stream>>>(qb, kb, vtb, partN, partL);
  combine_flash<<<192, 256, 0, stream>>>(partN, partL, o1);
  gemm_nt<1><<<dim3(6, 64), 256, 0, stream>>>(o1, pwb, proj_b, st, nullptr, nullptr, nullptr);
  flash_attn<2><<<dim3(32, 24), 256, 0, stream>>>(st, st, vtb, partN, partL);
  combine_flash<<<192, 256, 0, stream>>>(partN, partL, o2);
  gemm_nt<2><<<dim3(6, 64), 256, 0, stream>>>(o2, pwb, proj_b, nullptr, nullptr, nullptr, out);
}

// Round 12
// 231.873 us; speedup vs baseline: 1.1565x; 1.1565x over previous
//
#include <hip/hip_runtime.h>

typedef unsigned short u16;
typedef __bf16 bf16_t;
typedef bf16_t bf16x8 __attribute__((ext_vector_type(8)));
typedef float f32x4 __attribute__((ext_vector_type(4)));

static __device__ __forceinline__ u16 f2bf(float f) {
  unsigned u = __builtin_bit_cast(unsigned, f);
  u += 0x7FFFu + ((u >> 16) & 1u);
  return (u16)(u >> 16);
}
static __device__ __forceinline__ bf16x8 ldfrag(const u16* p) {
  return __builtin_bit_cast(bf16x8, *(const uint4*)p);
}
static __device__ __forceinline__ float fexp2(float x) {
#if __has_builtin(__builtin_amdgcn_exp2f)
  return __builtin_amdgcn_exp2f(x);
#else
  return __expf(x * 0.69314718056f);
#endif
}
// pack [hi.b3 hi.b2 lo.b3 lo.b2] (two bf16 = fp32 high halves, RTZ)
static __device__ __forceinline__ unsigned pack_hi16(unsigned hi, unsigned lo) {
#if __has_builtin(__builtin_amdgcn_perm)
  return __builtin_amdgcn_perm(hi, lo, 0x07060302u);
#else
  return (lo >> 16) | (hi & 0xFFFF0000u);
#endif
}
// XOR-swizzled tile: logical (row, 8-elem chunk) -> u16 offset, stride 64.
static __device__ __forceinline__ int sw(int row, int chunk) {
  return (row << 6) + ((chunk ^ (row & 7)) << 3);
}

#define XSZ 3145728   // 2*2048*768
#define QWSZ 1769472  // 2304*768
#define PWSZ 589824   // 768*768

// fp32 -> bf16 (RNE) one-shot conversion of x and the two weight matrices.
__global__ __launch_bounds__(256) void convert_all(
    const float* __restrict__ x, const float* __restrict__ qw,
    const float* __restrict__ pw, u16* __restrict__ xb,
    u16* __restrict__ qwb, u16* __restrict__ pwb)
{
  const int i = (blockIdx.x * 256 + threadIdx.x) * 8;
  const float* src; u16* dst; int off;
  if (i < XSZ) { src = x; dst = xb; off = i; }
  else if (i < XSZ + QWSZ) { src = qw; dst = qwb; off = i - XSZ; }
  else { src = pw; dst = pwb; off = i - (XSZ + QWSZ); }
  float4 a = *(const float4*)(src + off), b = *(const float4*)(src + off + 4);
  u16 t[8] = {f2bf(a.x), f2bf(a.y), f2bf(a.z), f2bf(a.w),
              f2bf(b.x), f2bf(b.y), f2bf(b.z), f2bf(b.w)};
  *(uint4*)(dst + off) = *(const uint4*)t;
}

// ---------------------------------------------------------------------------
// NT GEMM (all-bf16): C[m,n] = sum_k A[m,k] W[n,k] + bias[n]. K=768.
// BM=64, BN=128, swizzled LDS (48 KB), double-buffered, register prefetch,
// ONE barrier per K-iter, 3 blocks/CU.
// MODE 0: A=xb [B,N,C], grid(18,64): q,k -> [BH,N,D], V^T fused
// MODE 1: A=o1 [N,B,C], grid(6,64): fused L2-normalize -> st
// MODE 2: A=o2 [N,B,C], grid(6,64): -> fp32 d_out [B,N,C]
// ---------------------------------------------------------------------------
template<int MODE>
__global__ __launch_bounds__(256, 3) void gemm_nt(
    const u16* __restrict__ A, const u16* __restrict__ W,
    const float* __restrict__ bias,
    u16* __restrict__ d0, u16* __restrict__ d1, u16* __restrict__ d2,
    float* __restrict__ df)
{
  __shared__ __align__(16) u16 sA[2][64 * 64];
  __shared__ __align__(16) u16 sB[2][128 * 64];
  const int tid = threadIdx.x;
  const int m0 = blockIdx.y * 64, n0 = blockIdx.x * 128;
  const int w = tid >> 6, lane = tid & 63, l16 = lane & 15, quad = lane >> 4;
  const int wm = (w >> 1) * 32, wn = (w & 1) * 64;

  f32x4 acc[2][4] = {};
  const int sr = tid >> 3, ch = tid & 7, sc = ch * 8;

  #pragma unroll
  for (int p = 0; p < 2; p++)
    *(uint4*)(sA[0] + sw(sr + p * 32, ch)) =
        *(const uint4*)(A + (size_t)(m0 + sr + p * 32) * 768 + sc);
  #pragma unroll
  for (int p = 0; p < 4; p++)
    *(uint4*)(sB[0] + sw(sr + p * 32, ch)) =
        *(const uint4*)(W + (size_t)(n0 + sr + p * 32) * 768 + sc);
  __syncthreads();

  for (int kt = 0; kt < 12; kt++) {
    const int buf = kt & 1;
    const bool pre = (kt + 1 < 12);
    uint4 rab[2], rb[4];
    if (pre) {
      const int kc = (kt + 1) * 64 + sc;
      #pragma unroll
      for (int p = 0; p < 2; p++)
        rab[p] = *(const uint4*)(A + (size_t)(m0 + sr + p * 32) * 768 + kc);
      #pragma unroll
      for (int p = 0; p < 4; p++)
        rb[p] = *(const uint4*)(W + (size_t)(n0 + sr + p * 32) * 768 + kc);
    }
    #pragma unroll
    for (int ks = 0; ks < 2; ks++) {
      bf16x8 af[2], bfv[4];
      #pragma unroll
      for (int i = 0; i < 2; i++)
        af[i] = ldfrag(sA[buf] + sw(wm + i * 16 + l16, ks * 4 + quad));
      #pragma unroll
      for (int i = 0; i < 4; i++)
        bfv[i] = ldfrag(sB[buf] + sw(wn + i * 16 + l16, ks * 4 + quad));
      #pragma unroll
      for (int mi = 0; mi < 2; mi++)
        #pragma unroll
        for (int ni = 0; ni < 4; ni++)
          acc[mi][ni] = __builtin_amdgcn_mfma_f32_16x16x32_bf16(af[mi], bfv[ni], acc[mi][ni], 0, 0, 0);
    }
    if (pre) {
      #pragma unroll
      for (int p = 0; p < 2; p++)
        *(uint4*)(sA[buf ^ 1] + sw(sr + p * 32, ch)) = rab[p];
      #pragma unroll
      for (int p = 0; p < 4; p++)
        *(uint4*)(sB[buf ^ 1] + sw(sr + p * 32, ch)) = rb[p];
    }
    __syncthreads();
  }

  if (MODE == 0) {
    #pragma unroll
    for (int ni = 0; ni < 4; ni++) {
      const int gn = n0 + wn + ni * 16 + l16;
      const float bv = bias[gn];
      const int which = gn / 768;
      const int c = gn - which * 768, hh = c >> 6, d = c & 63;
      #pragma unroll
      for (int mi = 0; mi < 2; mi++) {
        const int gm0 = m0 + wm + mi * 16 + quad * 4;
        const int bb = gm0 >> 11, nt0 = gm0 & 2047;
        if (which == 2) {
          u16 t[4];
          #pragma unroll
          for (int r = 0; r < 4; r++) t[r] = f2bf(acc[mi][ni][r] + bv);
          *(uint2*)(d2 + (((size_t)(bb * 12 + hh)) * 64 + d) * 2048 + nt0) =
              *(const uint2*)t;
        } else {
          u16* dst = (which == 0) ? d0 : d1;
          #pragma unroll
          for (int r = 0; r < 4; r++)
            dst[(((size_t)(bb * 12 + hh)) * 2048 + nt0 + r) * 64 + d] =
                f2bf(acc[mi][ni][r] + bv);
        }
      }
    }
  } else if (MODE == 1) {
    #pragma unroll
    for (int mi = 0; mi < 2; mi++) {
      #pragma unroll
      for (int r = 0; r < 4; r++) {
        float v[4]; float ss = 0.f;
        #pragma unroll
        for (int ni = 0; ni < 4; ni++) {
          v[ni] = acc[mi][ni][r] + bias[n0 + wn + ni * 16 + l16];
          ss += v[ni] * v[ni];
        }
        #pragma unroll
        for (int off = 1; off < 16; off <<= 1) ss += __shfl_xor(ss, off);
        const float scl = 1.f / fmaxf(sqrtf(ss), 1e-12f);
        const int gm = m0 + wm + mi * 16 + quad * 4 + r;
        const int nt = gm >> 1, b = gm & 1;
        #pragma unroll
        for (int ni = 0; ni < 4; ni++) {
          const int gn = n0 + wn + ni * 16 + l16, h = gn >> 6, d = gn & 63;
          d0[(((size_t)(b * 12 + h)) * 2048 + nt) * 64 + d] = f2bf(v[ni] * scl);
        }
      }
    }
  } else {
    #pragma unroll
    for (int ni = 0; ni < 4; ni++) {
      const int gn = n0 + wn + ni * 16 + l16;
      const float bv = bias[gn];
      #pragma unroll
      for (int mi = 0; mi < 2; mi++) {
        #pragma unroll
        for (int r = 0; r < 4; r++) {
          const int gm = m0 + wm + mi * 16 + quad * 4 + r;
          const int nt = gm >> 1, b = gm & 1;
          df[((size_t)b * 2048 + nt) * 768 + gn] = acc[mi][ni][r] + bv;
        }
      }
    }
  }
}

// ---------------------------------------------------------------------------
// Flash attention, S^T form, KEY-SPLIT x2, double-buffered K/V (48 KB LDS,
// 3 blocks/CU), ONE barrier per iter. 256 threads = 4 waves; each wave owns
// 32 queries (2 groups of 16 sharing all K/V fragment reads). Q-tile = 128;
// each block does HALF the keys (16 j-iters), stores f32 partial numerators
// (128q x 64d = 8192 floats/block) + partial l. blockIdx.x = qt*2 + half.
// MODE 1: s*0.125;  MODE 2: s*10, s<0 masked.
// ---------------------------------------------------------------------------
template<int MODE>
__global__ __launch_bounds__(256, 2) void flash_attn(
    const u16* __restrict__ Qm, const u16* __restrict__ Km,
    const u16* __restrict__ VT,
    float* __restrict__ partN, float* __restrict__ partL)
{
  constexpr int N = 2048;
  __shared__ __align__(16) u16 sU[128 * 64];  // Q staging, then per-wave P
  __shared__ __align__(16) u16 sK[2][64 * 64];
  __shared__ __align__(16) u16 sVT[2][64 * 64];
  const int tid = threadIdx.x;
  const int bh = blockIdx.y;
  const int qt = blockIdx.x >> 1, half = blockIdx.x & 1;
  const int m0 = qt * 128, j0 = half * 1024;
  const int w = tid >> 6, lane = tid & 63, l16 = lane & 15, quad = lane >> 4;

  constexpr float SC = (MODE == 1) ? 0.18033688011112042f   // 0.125*log2(e)
                                   : 14.426950408889634f;   // 10*log2(e)
  constexpr float M0 = (MODE == 1) ? 24.f : 14.6f;

  const u16* kbase = Km + (size_t)bh * N * 64;
  const u16* vbase = VT + (size_t)bh * 64 * N;
  // Q staging: 128 rows x 8 chunks = 1024 uint4 over 256 threads (4 each)
  const int qr = tid >> 1, qc = (tid & 1) * 4;
  // K/V staging: 64 rows x 8 chunks = 512 uint4 over 256 threads (2 each)
  const int sr4 = tid >> 2, c4 = tid & 3;
  {
    const u16* qp = Qm + ((size_t)bh * N + m0 + qr) * 64 + qc * 8;
    #pragma unroll
    for (int j = 0; j < 4; j++)
      *(uint4*)(sU + sw(qr, qc + j)) = *(const uint4*)(qp + j * 8);
    const u16* kp = kbase + (size_t)(j0 + sr4) * 64;
    *(uint4*)(sK[0] + sw(sr4, c4))     = *(const uint4*)(kp + c4 * 8);
    *(uint4*)(sK[0] + sw(sr4, c4 + 4)) = *(const uint4*)(kp + c4 * 8 + 32);
    const u16* vp = vbase + (size_t)sr4 * N + j0;
    *(uint4*)(sVT[0] + sw(sr4, c4))     = *(const uint4*)(vp + c4 * 8);
    *(uint4*)(sVT[0] + sw(sr4, c4 + 4)) = *(const uint4*)(vp + c4 * 8 + 32);
  }
  __syncthreads();
  bf16x8 qf[2][2];
  #pragma unroll
  for (int qg = 0; qg < 2; qg++) {
    qf[qg][0] = ldfrag(sU + sw(w * 32 + qg * 16 + l16, quad));
    qf[qg][1] = ldfrag(sU + sw(w * 32 + qg * 16 + l16, quad + 4));
  }
  asm volatile("s_waitcnt lgkmcnt(0)" ::: "memory");  // qf in regs before P overlays

  bf16x8 ones;
  #pragma unroll
  for (int i = 0; i < 8; i++) ones[i] = (bf16_t)1.0f;

  f32x4 oacc[2][4] = {};
  f32x4 lacc[2] = {};

  for (int it = 0; it < 16; it++) {
    const int buf = it & 1;
    const u16* sKb = sK[buf];
    const u16* sVb = sVT[buf];
    u16* sKn = sK[buf ^ 1];
    u16* sVn = sVT[buf ^ 1];

    uint4 pk0, pk1, pv0, pv1;
    const bool pre = (it + 1 < 16);
    if (pre) {  // register prefetch of next tile (global latency overlapped)
      const int j1 = j0 + (it + 1) * 64;
      const u16* kp = kbase + (size_t)(j1 + sr4) * 64;
      pk0 = *(const uint4*)(kp + c4 * 8);
      pk1 = *(const uint4*)(kp + c4 * 8 + 32);
      const u16* vp = vbase + (size_t)sr4 * N + j1;
      pv0 = *(const uint4*)(vp + c4 * 8);
      pv1 = *(const uint4*)(vp + c4 * 8 + 32);
    }

    // S^T: D[m=key][n=query] = K . Q^T; kf shared across both query groups
    f32x4 s[2][4];
    #pragma unroll
    for (int jt = 0; jt < 4; jt++) {
      bf16x8 kf0 = ldfrag(sKb + sw(jt * 16 + l16, quad));
      bf16x8 kf1 = ldfrag(sKb + sw(jt * 16 + l16, quad + 4));
      #pragma unroll
      for (int qg = 0; qg < 2; qg++) {
        f32x4 a = {};
        a = __builtin_amdgcn_mfma_f32_16x16x32_bf16(kf0, qf[qg][0], a, 0, 0, 0);
        a = __builtin_amdgcn_mfma_f32_16x16x32_bf16(kf1, qf[qg][1], a, 0, 0, 0);
        s[qg][jt] = a;
      }
    }

    // p = exp2(s*SC - M0), masked->0; write own P rows (w*32 + qg*16 + l16)
    #pragma unroll
    for (int qg = 0; qg < 2; qg++) {
      const int prow = w * 32 + qg * 16 + l16;
      #pragma unroll
      for (int jt = 0; jt < 4; jt++) {
        unsigned pu[4];
        #pragma unroll
        for (int r = 0; r < 4; r++) {
          const float a = s[qg][jt][r];
          float p = fexp2(fmaf(a, SC, -M0));
          if (MODE == 2 && a < 0.f) p = 0.f;
          pu[r] = __builtin_bit_cast(unsigned, p) & 0xFFFF0000u;
        }
        uint2 pkk;
        pkk.x = pack_hi16(pu[1], pu[0]);
        pkk.y = pack_hi16(pu[3], pu[2]);
        *(uint2*)(sU + sw(prow, 2 * jt + (quad >> 1)) + (quad & 1) * 4) = pkk;
      }
    }

    // wave-local drain: P writes complete before B-layout re-read
    asm volatile("s_waitcnt lgkmcnt(0)" ::: "memory");
    bf16x8 pf[2][2];
    #pragma unroll
    for (int qg = 0; qg < 2; qg++) {
      pf[qg][0] = ldfrag(sU + sw(w * 32 + qg * 16 + l16, quad));
      pf[qg][1] = ldfrag(sU + sw(w * 32 + qg * 16 + l16, quad + 4));
    }

    if (pre) {  // LDS-write the prefetched tile (other buffer, no reader yet)
      *(uint4*)(sKn + sw(sr4, c4))     = pk0;
      *(uint4*)(sKn + sw(sr4, c4 + 4)) = pk1;
      *(uint4*)(sVn + sw(sr4, c4))     = pv0;
      *(uint4*)(sVn + sw(sr4, c4 + 4)) = pv1;
    }

    // O^T = V^T . P^T ; l = ones . P^T ; vf shared across query groups
    #pragma unroll
    for (int d4 = 0; d4 < 4; d4++) {
      bf16x8 v0 = ldfrag(sVb + sw(d4 * 16 + l16, quad));
      bf16x8 v1 = ldfrag(sVb + sw(d4 * 16 + l16, quad + 4));
      #pragma unroll
      for (int qg = 0; qg < 2; qg++) {
        oacc[qg][d4] = __builtin_amdgcn_mfma_f32_16x16x32_bf16(v0, pf[qg][0], oacc[qg][d4], 0, 0, 0);
        oacc[qg][d4] = __builtin_amdgcn_mfma_f32_16x16x32_bf16(v1, pf[qg][1], oacc[qg][d4], 0, 0, 0);
      }
    }
    #pragma unroll
    for (int qg = 0; qg < 2; qg++) {
      lacc[qg] = __builtin_amdgcn_mfma_f32_16x16x32_bf16(ones, pf[qg][0], lacc[qg], 0, 0, 0);
      lacc[qg] = __builtin_amdgcn_mfma_f32_16x16x32_bf16(ones, pf[qg][1], lacc[qg], 0, 0, 0);
    }
    __syncthreads();  // buf consumed by all waves; next buf visible
  }

  // store partials (no division): thread-flat, 8192 floats per block
  const int blk = bh * 32 + blockIdx.x;
  float* pN = partN + (size_t)blk * 8192 + tid * 32;
  #pragma unroll
  for (int qg = 0; qg < 2; qg++) {
    #pragma unroll
    for (int d4 = 0; d4 < 4; d4++)
      *(f32x4*)(pN + qg * 16 + d4 * 4) = oacc[qg][d4];
    if (quad == 0)
      partL[blk * 128 + w * 32 + qg * 16 + l16] = lacc[qg][0];
  }
}

// Combine the two key-halves: O = (n0+n1)/(l0+l1), write [N,B,C] bf16.
__global__ __launch_bounds__(256) void combine_flash(
    const float* __restrict__ partN, const float* __restrict__ partL,
    u16* __restrict__ Ob)
{
  const int pair = blockIdx.x;            // bh*16 + qt
  const int bh = pair >> 4, qt = pair & 15;
  const int b = bh / 12, h = bh % 12;
  const int m0 = qt * 128;
  const int tid = threadIdx.x;
  const int w = tid >> 6, lane = tid & 63, l16 = lane & 15, quad = lane >> 4;
  const int blk0 = bh * 32 + qt * 2, blk1 = blk0 + 1;
  const float* n0 = partN + (size_t)blk0 * 8192 + tid * 32;
  const float* n1 = partN + (size_t)blk1 * 8192 + tid * 32;
  #pragma unroll
  for (int qg = 0; qg < 2; qg++) {
    const int qrow = w * 32 + qg * 16 + l16;
    const float l0 = partL[blk0 * 128 + qrow];
    const float l1 = partL[blk1 * 128 + qrow];
    const float inv = 1.f / fmaxf(l0 + l1, 1e-30f);
    const int query = m0 + qrow;
    u16* obase = Ob + ((size_t)query * 2 + b) * 768 + h * 64;
    #pragma unroll
    for (int d4 = 0; d4 < 4; d4++) {
      float4 a = *(const float4*)(n0 + qg * 16 + d4 * 4);
      float4 c = *(const float4*)(n1 + qg * 16 + d4 * 4);
      u16 t[4] = {f2bf((a.x + c.x) * inv), f2bf((a.y + c.y) * inv),
                  f2bf((a.z + c.z) * inv), f2bf((a.w + c.w) * inv)};
      *(uint2*)(obase + d4 * 16 + quad * 4) = *(const uint2*)t;
    }
  }
}

extern "C" void kernel_launch(void* const* d_in, const int* in_sizes, int n_in,
                              void* d_out, int out_size, void* d_ws, size_t ws_size,
                              hipStream_t stream) {
  const float* x      = (const float*)d_in[0];
  const float* qkv_w  = (const float*)d_in[1];
  const float* qkv_b  = (const float*)d_in[2];
  const float* proj_w = (const float*)d_in[3];
  const float* proj_b = (const float*)d_in[4];
  float* out = (float*)d_out;

  const size_t SZ = (size_t)24 * 2048 * 64;  // elems per [BH,N,D] buffer
  char* ws = (char*)d_ws;
  u16* vtb = (u16*)ws;                                     // 6.29 MB
  size_t off = SZ * 2;
  u16* qwb = (u16*)(ws + off); off += (size_t)QWSZ * 2;    // 3.54 MB
  u16* pwb = (u16*)(ws + off); off += (size_t)PWSZ * 2;    // 1.18 MB
  u16* qb  = (u16*)(ws + off); off += SZ * 2;              // 6.29 MB
  u16* kb  = (u16*)(ws + off); off += SZ * 2;              // 6.29 MB
  float* partN = (float*)(ws + off); off += (size_t)768 * 8192 * 4;  // 25.2 MB
  float* partL = (float*)(ws + off); off += (size_t)768 * 128 * 4;   // 0.39 MB
  // overlays (time-disjoint): xb uses partN's region (xb dead after gemm0,
  // partN first written in flash1); o1/o2 reuse qb (dead after flash1);
  // st reuses kb (dead after flash1).
  u16* xb = (u16*)partN;
  u16* o1 = qb;
  u16* o2 = qb;
  u16* st = kb;
  // total ws use ~49.2 MB

  convert_all<<<2688, 256, 0, stream>>>(x, qkv_w, proj_w, xb, qwb, pwb);
  // q,k -> [BH,N,D]; V^T -> [BH,D,N] (transpose fused into epilogue)
  gemm_nt<0><<<dim3(18, 64), 256, 0, stream>>>(xb, qwb, qkv_b, qb, kb, vtb, nullptr);
  flash_attn<1><<<dim3(32, 24), 256, 0, stream>>>(qb, kb, vtb, partN, partL);
  combine_flash<<<384, 256, 0, stream>>>(partN, partL, o1);
  gemm_nt<1><<<dim3(6, 64), 256, 0, stream>>>(o1, pwb, proj_b, st, nullptr, nullptr, nullptr);
  flash_attn<2><<<dim3(32, 24), 256, 0, stream>>>(st, st, vtb, partN, partL);
  combine_flash<<<384, 256, 0, stream>>>(partN, partL, o2);
  gemm_nt<2><<<dim3(6, 64), 256, 0, stream>>>(o2, pwb, proj_b, nullptr, nullptr, nullptr, out);
}